// Round 1
// baseline (22537.772 us; speedup 1.0000x reference)
//
#include <hip/hip_runtime.h>
#include <hip/hip_bf16.h>
#include <math.h>

// Problem constants
#define NB       128
#define P_HW     196
#define ENC_C    2048
#define V_SZ     10000
#define E_SZ     512
#define D_SZ     512
#define MAXLEN   32
#define T_STEPS  31

// d_out layout (floats), in reference return order
#define SZ_PRED    (128ULL * 31ULL * 10000ULL)          // 39,680,000
#define OFF_PRED   0ULL
#define OFF_CAPT   (SZ_PRED)                            // 39,680,000
#define OFF_DECLEN (OFF_CAPT + 128ULL * 32ULL)          // 39,684,096
#define OFF_ALPHA  (OFF_DECLEN + 128ULL)                // 39,684,224
#define OFF_SORT   (OFF_ALPHA + 128ULL * 31ULL * 196ULL) // 40,461,952

__device__ __forceinline__ float sigf(float x) { return 1.0f / (1.0f + __expf(-x)); }

// ---------------------------------------------------------------------------
// Stable descending sort by caption length (rank via O(N^2) count), writes
// sorted int workspace + capt/dec_len/sort_ind float outputs.
// ---------------------------------------------------------------------------
__global__ void sort_kernel(const int* __restrict__ capt_lengths,
                            const int* __restrict__ enc_capt,
                            int* __restrict__ sort_ind_ws,
                            int* __restrict__ dec_len_ws,
                            int* __restrict__ capt_sorted_ws,
                            float* __restrict__ dout) {
    __shared__ int cl[NB];
    int i = threadIdx.x;
    cl[i] = capt_lengths[i];
    __syncthreads();
    int my = cl[i];
    int rank = 0;
    #pragma unroll 4
    for (int j = 0; j < NB; ++j) {
        int cj = cl[j];
        rank += (cj > my) || (cj == my && j < i);
    }
    sort_ind_ws[rank] = i;
    dec_len_ws[rank]  = my - 1;
    dout[OFF_SORT + rank]   = (float)i;
    dout[OFF_DECLEN + rank] = (float)(my - 1);
    for (int t = 0; t < MAXLEN; ++t) {
        int tok = enc_capt[i * MAXLEN + t];
        capt_sorted_ws[rank * MAXLEN + t] = tok;
        dout[OFF_CAPT + rank * MAXLEN + t] = (float)tok;
    }
}

// ---------------------------------------------------------------------------
// mean_feat[b, e] = mean over 196 positions of enc_feature[sort_ind[b], p, e]
// grid (8 chunks, 128 b), 256 threads
// ---------------------------------------------------------------------------
__global__ void mean_kernel(const float* __restrict__ enc_feature,
                            const int* __restrict__ sort_ind,
                            float* __restrict__ mean_feat) {
    int b = blockIdx.y;
    int e = blockIdx.x * 256 + threadIdx.x;
    int src = sort_ind[b];
    const float* base = enc_feature + (size_t)src * P_HW * ENC_C + e;
    float s = 0.0f;
    #pragma unroll 4
    for (int p = 0; p < P_HW; ++p) s += base[(size_t)p * ENC_C];
    mean_feat[(size_t)b * ENC_C + e] = s * (1.0f / (float)P_HW);
}

// ---------------------------------------------------------------------------
// Generic tiled f32 GEMM: C(128 x Nout) = A(128 x K) @ B(Nout x K)^T + bias
// BM=BN=64, BK=16, 256 threads, 4x4 per thread.
// EPI 0: plain (C, ldc)
// EPI 1: awe = mean_feat * sigmoid(.)  (C=awe, ldc)
// EPI 2: fc scatter: C=d_out, write (row*31+t)*10000+col, masked by dec_len
// ---------------------------------------------------------------------------
template <int EPI>
__global__ __launch_bounds__(256) void gemm_kernel(
    const float* __restrict__ A, int lda,
    const float* __restrict__ B, int ldb,
    const float* __restrict__ bias,
    float* __restrict__ C, int ldc,
    int Nout, int K,
    const float* __restrict__ meanfeat,
    const int* __restrict__ dec_len, int t) {
    __shared__ float As[64][16];
    __shared__ float Bs[64][16];
    int tid = threadIdx.x;
    int tx = tid & 15, ty = tid >> 4;
    int row0 = blockIdx.y * 64, col0 = blockIdx.x * 64;
    int lr = tid >> 2, lc = (tid & 3) << 2;
    float acc[4][4] = {};

    for (int k0 = 0; k0 < K; k0 += 16) {
        float4 av = *reinterpret_cast<const float4*>(A + (size_t)(row0 + lr) * lda + k0 + lc);
        float4 bv = make_float4(0.f, 0.f, 0.f, 0.f);
        int bn = col0 + lr;
        if (bn < Nout) bv = *reinterpret_cast<const float4*>(B + (size_t)bn * ldb + k0 + lc);
        *reinterpret_cast<float4*>(&As[lr][lc]) = av;
        *reinterpret_cast<float4*>(&Bs[lr][lc]) = bv;
        __syncthreads();
        #pragma unroll
        for (int kk = 0; kk < 16; ++kk) {
            float a0 = As[ty * 4 + 0][kk], a1 = As[ty * 4 + 1][kk];
            float a2 = As[ty * 4 + 2][kk], a3 = As[ty * 4 + 3][kk];
            float b0 = Bs[tx * 4 + 0][kk], b1 = Bs[tx * 4 + 1][kk];
            float b2 = Bs[tx * 4 + 2][kk], b3 = Bs[tx * 4 + 3][kk];
            acc[0][0] += a0 * b0; acc[0][1] += a0 * b1; acc[0][2] += a0 * b2; acc[0][3] += a0 * b3;
            acc[1][0] += a1 * b0; acc[1][1] += a1 * b1; acc[1][2] += a1 * b2; acc[1][3] += a1 * b3;
            acc[2][0] += a2 * b0; acc[2][1] += a2 * b1; acc[2][2] += a2 * b2; acc[2][3] += a2 * b3;
            acc[3][0] += a3 * b0; acc[3][1] += a3 * b1; acc[3][2] += a3 * b2; acc[3][3] += a3 * b3;
        }
        __syncthreads();
    }

    #pragma unroll
    for (int i = 0; i < 4; ++i) {
        int row = row0 + ty * 4 + i;
        #pragma unroll
        for (int j = 0; j < 4; ++j) {
            int col = col0 + tx * 4 + j;
            if (col < Nout) {
                float v = acc[i][j] + bias[col];
                if (EPI == 0) {
                    C[(size_t)row * ldc + col] = v;
                } else if (EPI == 1) {
                    C[(size_t)row * ldc + col] =
                        meanfeat[(size_t)row * ldc + col] * sigf(v);
                } else {
                    bool m = t < dec_len[row];
                    C[OFF_PRED + ((size_t)row * 31 + t) * 10000 + col] = m ? v : 0.0f;
                }
            }
        }
    }
}

// ---------------------------------------------------------------------------
// LSTM gate GEMM with composite virtual A = [emb(e_t) | awe | h], K=3072,
// B = [W_ih | W_hh], Nout=2048. g = A@B^T + b_ih + b_hh
// ---------------------------------------------------------------------------
__global__ __launch_bounds__(256) void gemm_lstm_kernel(
    const float* __restrict__ emb,
    const float* __restrict__ awe,
    const float* __restrict__ h,
    const float* __restrict__ W_ih,
    const float* __restrict__ W_hh,
    const float* __restrict__ b_ih,
    const float* __restrict__ b_hh,
    const int* __restrict__ capt_sorted, int t,
    float* __restrict__ g) {
    __shared__ float As[64][16];
    __shared__ float Bs[64][16];
    int tid = threadIdx.x;
    int tx = tid & 15, ty = tid >> 4;
    int row0 = blockIdx.y * 64, col0 = blockIdx.x * 64;
    int lr = tid >> 2, lc = (tid & 3) << 2;
    int arow = row0 + lr;
    int bn = col0 + lr;
    int tok = capt_sorted[arow * MAXLEN + t];
    float acc[4][4] = {};

    for (int k0 = 0; k0 < 3072; k0 += 16) {
        int k = k0 + lc;
        float4 av, bv;
        if (k0 < 512) {
            av = *reinterpret_cast<const float4*>(emb + (size_t)tok * E_SZ + k);
        } else if (k0 < 2560) {
            av = *reinterpret_cast<const float4*>(awe + (size_t)arow * ENC_C + (k - 512));
        } else {
            av = *reinterpret_cast<const float4*>(h + (size_t)arow * D_SZ + (k - 2560));
        }
        if (k0 < 2560) {
            bv = *reinterpret_cast<const float4*>(W_ih + (size_t)bn * 2560 + k);
        } else {
            bv = *reinterpret_cast<const float4*>(W_hh + (size_t)bn * D_SZ + (k - 2560));
        }
        *reinterpret_cast<float4*>(&As[lr][lc]) = av;
        *reinterpret_cast<float4*>(&Bs[lr][lc]) = bv;
        __syncthreads();
        #pragma unroll
        for (int kk = 0; kk < 16; ++kk) {
            float a0 = As[ty * 4 + 0][kk], a1 = As[ty * 4 + 1][kk];
            float a2 = As[ty * 4 + 2][kk], a3 = As[ty * 4 + 3][kk];
            float b0 = Bs[tx * 4 + 0][kk], b1 = Bs[tx * 4 + 1][kk];
            float b2 = Bs[tx * 4 + 2][kk], b3 = Bs[tx * 4 + 3][kk];
            acc[0][0] += a0 * b0; acc[0][1] += a0 * b1; acc[0][2] += a0 * b2; acc[0][3] += a0 * b3;
            acc[1][0] += a1 * b0; acc[1][1] += a1 * b1; acc[1][2] += a1 * b2; acc[1][3] += a1 * b3;
            acc[2][0] += a2 * b0; acc[2][1] += a2 * b1; acc[2][2] += a2 * b2; acc[2][3] += a2 * b3;
            acc[3][0] += a3 * b0; acc[3][1] += a3 * b1; acc[3][2] += a3 * b2; acc[3][3] += a3 * b3;
        }
        __syncthreads();
    }

    #pragma unroll
    for (int i = 0; i < 4; ++i) {
        int row = row0 + ty * 4 + i;
        #pragma unroll
        for (int j = 0; j < 4; ++j) {
            int col = col0 + tx * 4 + j;
            g[(size_t)row * 2048 + col] = acc[i][j] + b_ih[col] + b_hh[col];
        }
    }
}

// ---------------------------------------------------------------------------
// LSTM pointwise: c_new/h_new + masked update of h, c
// ---------------------------------------------------------------------------
__global__ void lstm_pointwise(const float* __restrict__ g,
                               float* __restrict__ h,
                               float* __restrict__ c,
                               float* __restrict__ h_new,
                               const int* __restrict__ dec_len, int t) {
    int idx = blockIdx.x * 256 + threadIdx.x;  // 128*512 = 65536
    int b = idx >> 9, d = idx & 511;
    const float* gb = g + (size_t)b * 2048;
    float gi = gb[d], gf = gb[512 + d], gg = gb[1024 + d], go = gb[1536 + d];
    float cn = sigf(gf) * c[idx] + sigf(gi) * tanhf(gg);
    float hn = sigf(go) * tanhf(cn);
    h_new[idx] = hn;
    if (t < dec_len[b]) {
        h[idx] = hn;
        c[idx] = cn;
    }
}

// ---------------------------------------------------------------------------
// alphas[b, t, p] = (t < dec_len[b]) / 196
// ---------------------------------------------------------------------------
__global__ void alphas_kernel(const int* __restrict__ dec_len,
                              float* __restrict__ dout) {
    int idx = blockIdx.x * 256 + threadIdx.x;  // exactly 777728
    int b = idx / (31 * 196);
    int r = idx % (31 * 196);
    int t = r / 196;
    dout[OFF_ALPHA + idx] = (t < dec_len[b]) ? (1.0f / 196.0f) : 0.0f;
}

// ---------------------------------------------------------------------------
extern "C" void kernel_launch(void* const* d_in, const int* in_sizes, int n_in,
                              void* d_out, int out_size, void* d_ws, size_t ws_size,
                              hipStream_t stream) {
    const float* enc_feature  = (const float*)d_in[0];
    const int*   enc_capt     = (const int*)d_in[1];
    const int*   capt_lengths = (const int*)d_in[2];
    const float* emb     = (const float*)d_in[3];
    const float* W_ih    = (const float*)d_in[4];
    const float* b_ih    = (const float*)d_in[5];
    const float* W_hh    = (const float*)d_in[6];
    const float* b_hh    = (const float*)d_in[7];
    const float* W_inith = (const float*)d_in[8];
    const float* b_inith = (const float*)d_in[9];
    const float* W_initc = (const float*)d_in[10];
    const float* b_initc = (const float*)d_in[11];
    const float* W_fbeta = (const float*)d_in[12];
    const float* b_fbeta = (const float*)d_in[13];
    const float* W_fc    = (const float*)d_in[14];
    const float* b_fc    = (const float*)d_in[15];
    float* out = (float*)d_out;

    char* ws = (char*)d_ws;
    int* sort_ind    = (int*)ws;            ws += 128 * sizeof(int);
    int* dec_len     = (int*)ws;            ws += 128 * sizeof(int);
    int* capt_sorted = (int*)ws;            ws += 128 * MAXLEN * sizeof(int);
    float* mean_feat = (float*)ws;          ws += (size_t)128 * 2048 * sizeof(float);
    float* h         = (float*)ws;          ws += (size_t)128 * 512 * sizeof(float);
    float* c         = (float*)ws;          ws += (size_t)128 * 512 * sizeof(float);
    float* h_new     = (float*)ws;          ws += (size_t)128 * 512 * sizeof(float);
    float* awe       = (float*)ws;          ws += (size_t)128 * 2048 * sizeof(float);
    float* g         = (float*)ws;          ws += (size_t)128 * 2048 * sizeof(float);

    sort_kernel<<<1, 128, 0, stream>>>(capt_lengths, enc_capt, sort_ind, dec_len,
                                       capt_sorted, out);
    mean_kernel<<<dim3(8, 128), 256, 0, stream>>>(enc_feature, sort_ind, mean_feat);

    // h0 = mean_feat @ W_inith^T + b_inith ; c0 likewise
    gemm_kernel<0><<<dim3(8, 2), 256, 0, stream>>>(
        mean_feat, 2048, W_inith, 2048, b_inith, h, 512, 512, 2048,
        nullptr, nullptr, 0);
    gemm_kernel<0><<<dim3(8, 2), 256, 0, stream>>>(
        mean_feat, 2048, W_initc, 2048, b_initc, c, 512, 512, 2048,
        nullptr, nullptr, 0);

    for (int t = 0; t < T_STEPS; ++t) {
        // awe = mean_feat * sigmoid(h @ W_fbeta^T + b_fbeta)
        gemm_kernel<1><<<dim3(32, 2), 256, 0, stream>>>(
            h, 512, W_fbeta, 512, b_fbeta, awe, 2048, 2048, 512,
            mean_feat, nullptr, 0);
        // g = [e_t | awe | h] @ [W_ih | W_hh]^T + b_ih + b_hh
        gemm_lstm_kernel<<<dim3(32, 2), 256, 0, stream>>>(
            emb, awe, h, W_ih, W_hh, b_ih, b_hh, capt_sorted, t, g);
        // LSTM pointwise + masked state update
        lstm_pointwise<<<256, 256, 0, stream>>>(g, h, c, h_new, dec_len, t);
        // preds[:, t, :] = (h_new @ W_fc^T + b_fc) * mask
        gemm_kernel<2><<<dim3(157, 2), 256, 0, stream>>>(
            h_new, 512, W_fc, 512, b_fc, out, 0, 10000, 512,
            nullptr, dec_len, t);
    }

    alphas_kernel<<<3038, 256, 0, stream>>>(dec_len, out);
}

// Round 2
// 2205.560 us; speedup vs baseline: 10.2186x; 10.2186x over previous
//
#include <hip/hip_runtime.h>
#include <hip/hip_bf16.h>
#include <math.h>

// Problem constants
#define NB       128
#define P_HW     196
#define ENC_C    2048
#define V_SZ     10000
#define E_SZ     512
#define D_SZ     512
#define MAXLEN   32
#define T_STEPS  31

// d_out layout (floats), in reference return order
#define SZ_PRED    (128ULL * 31ULL * 10000ULL)
#define OFF_PRED   0ULL
#define OFF_CAPT   (SZ_PRED)
#define OFF_DECLEN (OFF_CAPT + 128ULL * 32ULL)
#define OFF_ALPHA  (OFF_DECLEN + 128ULL)
#define OFF_SORT   (OFF_ALPHA + 128ULL * 31ULL * 196ULL)

typedef __bf16 bf16x8 __attribute__((ext_vector_type(8)));
typedef float f32x4 __attribute__((ext_vector_type(4)));

__device__ __forceinline__ float sigf(float x) { return 1.0f / (1.0f + __expf(-x)); }

__device__ __forceinline__ unsigned short f2bf(float f) {
    unsigned int u = __float_as_uint(f);
    unsigned int r = (u + 0x7fffu + ((u >> 16) & 1u)) >> 16;  // RNE
    return (unsigned short)r;
}

// ---------------------------------------------------------------------------
// Stable descending sort by caption length (rank via O(N^2) count)
// ---------------------------------------------------------------------------
__global__ void sort_kernel(const int* __restrict__ capt_lengths,
                            const int* __restrict__ enc_capt,
                            int* __restrict__ sort_ind_ws,
                            int* __restrict__ dec_len_ws,
                            int* __restrict__ capt_sorted_ws,
                            float* __restrict__ dout) {
    __shared__ int cl[NB];
    int i = threadIdx.x;
    cl[i] = capt_lengths[i];
    __syncthreads();
    int my = cl[i];
    int rank = 0;
    #pragma unroll 4
    for (int j = 0; j < NB; ++j) {
        int cj = cl[j];
        rank += (cj > my) || (cj == my && j < i);
    }
    sort_ind_ws[rank] = i;
    dec_len_ws[rank]  = my - 1;
    dout[OFF_SORT + rank]   = (float)i;
    dout[OFF_DECLEN + rank] = (float)(my - 1);
    for (int t = 0; t < MAXLEN; ++t) {
        int tok = enc_capt[i * MAXLEN + t];
        capt_sorted_ws[rank * MAXLEN + t] = tok;
        dout[OFF_CAPT + rank * MAXLEN + t] = (float)tok;
    }
}

// ---------------------------------------------------------------------------
// mean_feat[b, e] = mean over 196 positions; writes fp32 + bf16 copies
// ---------------------------------------------------------------------------
__global__ void mean_kernel(const float* __restrict__ enc_feature,
                            const int* __restrict__ sort_ind,
                            float* __restrict__ mean_feat,
                            unsigned short* __restrict__ mean16) {
    int b = blockIdx.y;
    int e = blockIdx.x * 256 + threadIdx.x;
    int src = sort_ind[b];
    const float* base = enc_feature + (size_t)src * P_HW * ENC_C + e;
    float s = 0.0f;
    #pragma unroll 4
    for (int p = 0; p < P_HW; ++p) s += base[(size_t)p * ENC_C];
    float m = s * (1.0f / (float)P_HW);
    mean_feat[(size_t)b * ENC_C + e] = m;
    mean16[(size_t)b * ENC_C + e] = f2bf(m);
}

// ---------------------------------------------------------------------------
// fp32 -> bf16 converts
// ---------------------------------------------------------------------------
__global__ void f32_to_bf16(const float* __restrict__ src,
                            unsigned short* __restrict__ dst, int n) {
    int i = (blockIdx.x * 256 + threadIdx.x) * 4;
    if (i < n) {
        float4 v = *reinterpret_cast<const float4*>(src + i);
        dst[i + 0] = f2bf(v.x);
        dst[i + 1] = f2bf(v.y);
        dst[i + 2] = f2bf(v.z);
        dst[i + 3] = f2bf(v.w);
    }
}

// Wg16[n][0:2560] = W_ih[n], Wg16[n][2560:3072] = W_hh[n]
__global__ void concat_wg(const float* __restrict__ W_ih,
                          const float* __restrict__ W_hh,
                          unsigned short* __restrict__ Wg16) {
    int n = blockIdx.y;
    int col = blockIdx.x * 256 + threadIdx.x;  // < 3072
    float v = (col < 2560) ? W_ih[(size_t)n * 2560 + col]
                           : W_hh[(size_t)n * 512 + (col - 2560)];
    Wg16[(size_t)n * 3072 + col] = f2bf(v);
}

__global__ void bsum_kernel(const float* __restrict__ b_ih,
                            const float* __restrict__ b_hh,
                            float* __restrict__ bsum) {
    int i = blockIdx.x * 256 + threadIdx.x;  // 2048
    bsum[i] = b_ih[i] + b_hh[i];
}

// embs16[t][b][e] = bf16(emb[capt_sorted[b][t]][e]), t in [0,31)
__global__ void embs_gather(const float* __restrict__ emb,
                            const int* __restrict__ capt_sorted,
                            unsigned short* __restrict__ embs16) {
    int idx = blockIdx.x * 256 + threadIdx.x;  // 31*128*512 = 2031616
    if (idx >= 31 * 128 * 512) return;
    int t = idx >> 16;            // /65536
    int r = idx & 65535;
    int b = r >> 9;
    int e = r & 511;
    int tok = capt_sorted[b * MAXLEN + t];
    embs16[idx] = f2bf(emb[(size_t)tok * E_SZ + e]);
}

// ---------------------------------------------------------------------------
// LDS-free MFMA GEMM: C(128 x Nout) = A(128 x K) @ B(Nout x K)^T
// 1 wave / block; 32x32 tile via 2x2 mfma_f32_16x16x32_bf16 fragments.
// EPI 0: Cf[row*ldc+col] = acc + bias[col]
// EPI 1: Cb (awe16) = bf16(meanfeat * sigmoid(acc + bias))
// EPI 2: fc scatter to d_out, masked by dec_len
// EPI 4: Cb = bf16(acc + bias)   (init h)
// ---------------------------------------------------------------------------
template <int EPI>
__global__ __launch_bounds__(64) void mfma_gemm(
    const unsigned short* __restrict__ A, int lda,
    const unsigned short* __restrict__ B, int ldb,
    int Nout, int K,
    const float* __restrict__ bias,
    float* __restrict__ Cf, unsigned short* __restrict__ Cb, int ldc,
    const float* __restrict__ meanfeat,
    const int* __restrict__ dec_len, int t) {
    int l = threadIdx.x;
    int lm = l & 15;
    int lk = (l >> 4) << 3;
    int row0 = blockIdx.y << 5;
    int col0 = blockIdx.x << 5;
    const unsigned short* pa0 = A + (size_t)(row0 + lm) * lda + lk;
    const unsigned short* pa1 = pa0 + ((size_t)lda << 4);
    int bn0 = col0 + lm;
    int bn1 = bn0 + 16;
    int cb0 = bn0 < Nout ? bn0 : Nout - 1;
    int cb1 = bn1 < Nout ? bn1 : Nout - 1;
    const unsigned short* pb0 = B + (size_t)cb0 * ldb + lk;
    const unsigned short* pb1 = B + (size_t)cb1 * ldb + lk;
    f32x4 acc00 = {0.f, 0.f, 0.f, 0.f}, acc01 = acc00, acc10 = acc00, acc11 = acc00;
    for (int k = 0; k < K; k += 32) {
        bf16x8 a0 = *(const bf16x8*)(pa0 + k);
        bf16x8 a1 = *(const bf16x8*)(pa1 + k);
        bf16x8 b0 = *(const bf16x8*)(pb0 + k);
        bf16x8 b1 = *(const bf16x8*)(pb1 + k);
        acc00 = __builtin_amdgcn_mfma_f32_16x16x32_bf16(a0, b0, acc00, 0, 0, 0);
        acc01 = __builtin_amdgcn_mfma_f32_16x16x32_bf16(a0, b1, acc01, 0, 0, 0);
        acc10 = __builtin_amdgcn_mfma_f32_16x16x32_bf16(a1, b0, acc10, 0, 0, 0);
        acc11 = __builtin_amdgcn_mfma_f32_16x16x32_bf16(a1, b1, acc11, 0, 0, 0);
    }
    int orow = (l >> 4) << 2;
    #pragma unroll
    for (int mi = 0; mi < 2; ++mi) {
        #pragma unroll
        for (int ni = 0; ni < 2; ++ni) {
            f32x4 v = (mi == 0) ? (ni == 0 ? acc00 : acc01)
                                : (ni == 0 ? acc10 : acc11);
            int col = col0 + ni * 16 + lm;
            if (col >= Nout) continue;
            #pragma unroll
            for (int r = 0; r < 4; ++r) {
                int row = row0 + mi * 16 + orow + r;
                float val = v[r] + bias[col];
                if (EPI == 0) {
                    Cf[(size_t)row * ldc + col] = val;
                } else if (EPI == 1) {
                    Cb[(size_t)row * ldc + col] =
                        f2bf(meanfeat[(size_t)row * ldc + col] * sigf(val));
                } else if (EPI == 2) {
                    bool m = t < dec_len[row];
                    Cf[OFF_PRED + ((size_t)row * 31 + t) * 10000 + col] = m ? val : 0.0f;
                } else {
                    Cb[(size_t)row * ldc + col] = f2bf(val);
                }
            }
        }
    }
}

// ---------------------------------------------------------------------------
// LSTM gate GEMM, composite A = [emb_t | awe | h] (K=3072), B = Wg16
// ---------------------------------------------------------------------------
__global__ __launch_bounds__(64) void mfma_lstm(
    const unsigned short* __restrict__ embt,   // 128 x 512 (this step)
    const unsigned short* __restrict__ awe16,  // 128 x 2048
    const unsigned short* __restrict__ h16,    // 128 x 512
    const unsigned short* __restrict__ Wg,     // 2048 x 3072
    const float* __restrict__ bsum,
    float* __restrict__ g) {
    int l = threadIdx.x;
    int lm = l & 15;
    int lk = (l >> 4) << 3;
    int row0 = blockIdx.y << 5;
    int col0 = blockIdx.x << 5;
    int r0 = row0 + lm, r1 = r0 + 16;
    const unsigned short* pe0 = embt + (size_t)r0 * 512 + lk;
    const unsigned short* pe1 = embt + (size_t)r1 * 512 + lk;
    const unsigned short* pw0 = awe16 + (size_t)r0 * 2048 + lk;
    const unsigned short* pw1 = awe16 + (size_t)r1 * 2048 + lk;
    const unsigned short* ph0 = h16 + (size_t)r0 * 512 + lk;
    const unsigned short* ph1 = h16 + (size_t)r1 * 512 + lk;
    const unsigned short* pb0 = Wg + (size_t)(col0 + lm) * 3072 + lk;
    const unsigned short* pb1 = pb0 + (size_t)16 * 3072;
    f32x4 acc00 = {0.f, 0.f, 0.f, 0.f}, acc01 = acc00, acc10 = acc00, acc11 = acc00;
    for (int k = 0; k < 3072; k += 32) {
        bf16x8 a0, a1;
        if (k < 512) {
            a0 = *(const bf16x8*)(pe0 + k);
            a1 = *(const bf16x8*)(pe1 + k);
        } else if (k < 2560) {
            a0 = *(const bf16x8*)(pw0 + (k - 512));
            a1 = *(const bf16x8*)(pw1 + (k - 512));
        } else {
            a0 = *(const bf16x8*)(ph0 + (k - 2560));
            a1 = *(const bf16x8*)(ph1 + (k - 2560));
        }
        bf16x8 b0 = *(const bf16x8*)(pb0 + k);
        bf16x8 b1 = *(const bf16x8*)(pb1 + k);
        acc00 = __builtin_amdgcn_mfma_f32_16x16x32_bf16(a0, b0, acc00, 0, 0, 0);
        acc01 = __builtin_amdgcn_mfma_f32_16x16x32_bf16(a0, b1, acc01, 0, 0, 0);
        acc10 = __builtin_amdgcn_mfma_f32_16x16x32_bf16(a1, b0, acc10, 0, 0, 0);
        acc11 = __builtin_amdgcn_mfma_f32_16x16x32_bf16(a1, b1, acc11, 0, 0, 0);
    }
    int orow = (l >> 4) << 2;
    #pragma unroll
    for (int mi = 0; mi < 2; ++mi) {
        #pragma unroll
        for (int ni = 0; ni < 2; ++ni) {
            f32x4 v = (mi == 0) ? (ni == 0 ? acc00 : acc01)
                                : (ni == 0 ? acc10 : acc11);
            int col = col0 + ni * 16 + lm;
            #pragma unroll
            for (int r = 0; r < 4; ++r) {
                int row = row0 + mi * 16 + orow + r;
                g[(size_t)row * 2048 + col] = v[r] + bsum[col];
            }
        }
    }
}

// ---------------------------------------------------------------------------
// LSTM pointwise: masked state update; h kept in bf16 (GEMM input form)
// ---------------------------------------------------------------------------
__global__ void lstm_pointwise(const float* __restrict__ g,
                               float* __restrict__ c,
                               unsigned short* __restrict__ h16,
                               unsigned short* __restrict__ hnew16,
                               const int* __restrict__ dec_len, int t) {
    int idx = blockIdx.x * 256 + threadIdx.x;  // 128*512
    int b = idx >> 9, d = idx & 511;
    const float* gb = g + ((size_t)b << 11);
    float gi = gb[d], gf = gb[512 + d], gg = gb[1024 + d], go = gb[1536 + d];
    float cn = sigf(gf) * c[idx] + sigf(gi) * tanhf(gg);
    float hn = sigf(go) * tanhf(cn);
    hnew16[idx] = f2bf(hn);
    if (t < dec_len[b]) {
        c[idx] = cn;
        h16[idx] = f2bf(hn);
    }
}

// ---------------------------------------------------------------------------
__global__ void alphas_kernel(const int* __restrict__ dec_len,
                              float* __restrict__ dout) {
    int idx = blockIdx.x * 256 + threadIdx.x;  // 777728
    int b = idx / (31 * 196);
    int r = idx % (31 * 196);
    int t = r / 196;
    dout[OFF_ALPHA + idx] = (t < dec_len[b]) ? (1.0f / 196.0f) : 0.0f;
}

// ---------------------------------------------------------------------------
static inline char* align256(char* p) {
    return (char*)(((uintptr_t)p + 255) & ~(uintptr_t)255);
}

extern "C" void kernel_launch(void* const* d_in, const int* in_sizes, int n_in,
                              void* d_out, int out_size, void* d_ws, size_t ws_size,
                              hipStream_t stream) {
    const float* enc_feature  = (const float*)d_in[0];
    const int*   enc_capt     = (const int*)d_in[1];
    const int*   capt_lengths = (const int*)d_in[2];
    const float* emb     = (const float*)d_in[3];
    const float* W_ih    = (const float*)d_in[4];
    const float* b_ih    = (const float*)d_in[5];
    const float* W_hh    = (const float*)d_in[6];
    const float* b_hh    = (const float*)d_in[7];
    const float* W_inith = (const float*)d_in[8];
    const float* b_inith = (const float*)d_in[9];
    const float* W_initc = (const float*)d_in[10];
    const float* b_initc = (const float*)d_in[11];
    const float* W_fbeta = (const float*)d_in[12];
    const float* b_fbeta = (const float*)d_in[13];
    const float* W_fc    = (const float*)d_in[14];
    const float* b_fc    = (const float*)d_in[15];
    float* out = (float*)d_out;

    char* ws = (char*)d_ws;
    int* sort_ind    = (int*)ws;  ws += 512;
    int* dec_len     = (int*)ws;  ws += 512;
    int* capt_sorted = (int*)ws;  ws += 128 * MAXLEN * sizeof(int);
    ws = align256(ws);
    float* mean_feat = (float*)ws; ws += (size_t)128 * 2048 * 4;
    float* c         = (float*)ws; ws += (size_t)128 * 512 * 4;
    float* g         = (float*)ws; ws += (size_t)128 * 2048 * 4;
    float* bsum      = (float*)ws; ws += 2048 * 4;
    unsigned short* mean16   = (unsigned short*)ws; ws += (size_t)128 * 2048 * 2;
    unsigned short* h16      = (unsigned short*)ws; ws += (size_t)128 * 512 * 2;
    unsigned short* hnew16   = (unsigned short*)ws; ws += (size_t)128 * 512 * 2;
    unsigned short* awe16    = (unsigned short*)ws; ws += (size_t)128 * 2048 * 2;
    unsigned short* Wfb16    = (unsigned short*)ws; ws += (size_t)2048 * 512 * 2;
    unsigned short* Wg16     = (unsigned short*)ws; ws += (size_t)2048 * 3072 * 2;
    unsigned short* Wfc16    = (unsigned short*)ws; ws += (size_t)10000 * 512 * 2;
    unsigned short* Winith16 = (unsigned short*)ws; ws += (size_t)512 * 2048 * 2;
    unsigned short* Winitc16 = (unsigned short*)ws; ws += (size_t)512 * 2048 * 2;
    unsigned short* embs16   = (unsigned short*)ws; ws += (size_t)31 * 128 * 512 * 2;

    sort_kernel<<<1, 128, 0, stream>>>(capt_lengths, enc_capt, sort_ind, dec_len,
                                       capt_sorted, out);
    mean_kernel<<<dim3(8, 128), 256, 0, stream>>>(enc_feature, sort_ind,
                                                  mean_feat, mean16);

    f32_to_bf16<<<(2048 * 512 / 4 + 255) / 256, 256, 0, stream>>>(W_fbeta, Wfb16, 2048 * 512);
    f32_to_bf16<<<(10000 * 512 / 4 + 255) / 256, 256, 0, stream>>>(W_fc, Wfc16, 10000 * 512);
    f32_to_bf16<<<(512 * 2048 / 4 + 255) / 256, 256, 0, stream>>>(W_inith, Winith16, 512 * 2048);
    f32_to_bf16<<<(512 * 2048 / 4 + 255) / 256, 256, 0, stream>>>(W_initc, Winitc16, 512 * 2048);
    concat_wg<<<dim3(12, 2048), 256, 0, stream>>>(W_ih, W_hh, Wg16);
    bsum_kernel<<<8, 256, 0, stream>>>(b_ih, b_hh, bsum);
    embs_gather<<<(31 * 128 * 512 + 255) / 256, 256, 0, stream>>>(emb, capt_sorted, embs16);

    // h0 (bf16) and c0 (fp32)
    mfma_gemm<4><<<dim3(16, 4), 64, 0, stream>>>(
        mean16, 2048, Winith16, 2048, 512, 2048, b_inith,
        nullptr, h16, 512, nullptr, nullptr, 0);
    mfma_gemm<0><<<dim3(16, 4), 64, 0, stream>>>(
        mean16, 2048, Winitc16, 2048, 512, 2048, b_initc,
        c, nullptr, 512, nullptr, nullptr, 0);

    for (int t = 0; t < T_STEPS; ++t) {
        // awe16 = bf16(mean_feat * sigmoid(h @ W_fbeta^T + b_fbeta))
        mfma_gemm<1><<<dim3(64, 4), 64, 0, stream>>>(
            h16, 512, Wfb16, 512, 2048, 512, b_fbeta,
            nullptr, awe16, 2048, mean_feat, nullptr, 0);
        // g = [emb_t | awe | h] @ Wg^T + bsum
        mfma_lstm<<<dim3(64, 4), 64, 0, stream>>>(
            embs16 + (size_t)t * 128 * 512, awe16, h16, Wg16, bsum, g);
        lstm_pointwise<<<256, 256, 0, stream>>>(g, c, h16, hnew16, dec_len, t);
        // preds[:, t, :] = (h_new @ W_fc^T + b_fc) * mask
        mfma_gemm<2><<<dim3(313, 4), 64, 0, stream>>>(
            hnew16, 512, Wfc16, 512, 10000, 512, b_fc,
            out, nullptr, 0, nullptr, dec_len, t);
    }

    alphas_kernel<<<3038, 256, 0, stream>>>(dec_len, out);
}